// Round 4
// baseline (224.346 us; speedup 1.0000x reference)
//
#include <hip/hip_runtime.h>

// GQA causal+segment-masked flash attention. fp32 in/out.
// B=2, T=2048, NQ=32 (8 kv heads x 4), D=128.
// R11: barrier-free, LDS-free main kernel. K/V fragments are loaded
// DIRECTLY from the prepped ws into registers (16x global_load_dwordx4
// per tile per wave, each a contiguous 1KB), double-buffered so loads of
// tile t+1 fly under compute of tile t (compiler-counted vmcnt). No
// __syncthreads, no LDS, no DMA drain convoy (R9/R10 showed invariant
// ~3240 cyc/block-tile from barrier-coupled staging). L1 serves the
// 4-waves-same-tile duplication. Keeps: swapped QK mfma(K,Q), in-register
// P transpose (cvt_pk_bf16 + permlane16/32_swap), unnormalized exp2 accum,
// folded causal pair grid (uniform blocks), setprio around MFMA.

typedef __bf16 bf16x8 __attribute__((ext_vector_type(8)));
typedef __bf16 bf16x2 __attribute__((ext_vector_type(2)));
typedef _Float16 f16x8 __attribute__((ext_vector_type(8)));
typedef float f32x4 __attribute__((ext_vector_type(4)));
typedef unsigned int uint2v __attribute__((ext_vector_type(2)));

#define B_   2
#define T_   2048
#define NQ_  32
#define NKV_ 8
#define D_   128

#define MASKV (-3.0e38f)
#define LOG2E 1.44269504f
#define TILE_US 8192           // ushorts per 32-col KV tile in ws: 8KB fp16 K + 8KB bf16 Vt
#define WS_TILES_BYTES ((size_t)B_ * NKV_ * (T_ / 32) * TILE_US * 2)   // 16777216
#define WS_NEED (WS_TILES_BYTES + (size_t)B_ * T_ * 4)

static __device__ __forceinline__ unsigned short f2bf(float x) {
    union { float f; unsigned int u; } c; c.f = x;
    unsigned int r = c.u + 0x7fffu + ((c.u >> 16) & 1u);
    return (unsigned short)(r >> 16);
}

union U8  { unsigned short us[8]; bf16x8 v; };
union H8  { _Float16 h[8]; f16x8 v; };
union PKW { bf16x2 h; unsigned int u; };
union PA4 { unsigned int u[4]; bf16x8 v; };

// register-pair lane swaps (gfx950): a[32:63] <-> b[0:31]  /  a[16:31]<->b[0:15], a[48:63]<->b[32:47]
static __device__ __forceinline__ void pl32swap(unsigned int& a, unsigned int& b) {
#if __has_builtin(__builtin_amdgcn_permlane32_swap)
    uint2v t = __builtin_amdgcn_permlane32_swap(a, b, false, false);
    a = t.x; b = t.y;
#else
    asm("s_nop 1\n\tv_permlane32_swap_b32 %0, %1" : "+v"(a), "+v"(b));
#endif
}
static __device__ __forceinline__ void pl16swap(unsigned int& a, unsigned int& b) {
#if __has_builtin(__builtin_amdgcn_permlane16_swap)
    uint2v t = __builtin_amdgcn_permlane16_swap(a, b, false, false);
    a = t.x; b = t.y;
#else
    asm("s_nop 1\n\tv_permlane16_swap_b32 %0, %1" : "+v"(a), "+v"(b));
#endif
}

// ---------------- prep 1: K -> fp16, V^T -> bf16, fragment-ordered ws tiles ----------------
// K region (ushort 0..4095):  16B slot = (c*2+hi)*64 + qd*16 + ln
//   holds K[row = hi*16+ln][d = c*32+qd*8 .. +7] as fp16.
//   -> wave load instr (c,hi): 64 lanes read contiguous 1KB at (c*2+hi)*512.
// V region (ushort 4096..8191): 16B slot = sub*64 + sc*16 + dln
//   holds V^T[d = sub*16+dln][kv = sc*8 .. +7] as bf16.
//   -> wave load instr (sub): contiguous 1KB at 4096 + sub*512.
__global__ __launch_bounds__(256)
void prep(const float* __restrict__ kg, const float* __restrict__ vg,
          unsigned short* __restrict__ ws)
{
    const int tid = threadIdx.x;
    const int st  = blockIdx.x;    // 32-col KV tile index
    const int kvh = blockIdx.y;
    const int b   = blockIdx.z;
    unsigned short* base = ws + ((size_t)((b * NKV_ + kvh) * (T_ / 32) + st)) * TILE_US;

    // K: 512 tasks = 32 rows x 16 chunks(8 elems), fp16
    #pragma unroll
    for (int it = 0; it < 2; ++it) {
        int task = tid + it * 256;
        int r = task >> 4, c16 = task & 15;            // d = c16*8
        const float* kp = kg + (((size_t)(b * T_ + st * 32 + r)) * NKV_ + kvh) * D_ + c16 * 8;
        H8 hu;
        #pragma unroll
        for (int j = 0; j < 8; ++j) hu.h[j] = (_Float16)kp[j];
        int c = c16 >> 2, qd = c16 & 3, hi = r >> 4, ln = r & 15;
        int slot = (c * 2 + hi) * 64 + qd * 16 + ln;
        *(f16x8*)(base + slot * 8) = hu.v;
    }
    // V^T: 512 tasks = 128 d x 4 s-chunks(8 s), bf16
    #pragma unroll
    for (int it = 0; it < 2; ++it) {
        int task = tid + it * 256;
        int d = task & 127, sc = task >> 7;
        const float* vp = vg + (((size_t)(b * T_ + st * 32 + sc * 8)) * NKV_ + kvh) * D_ + d;
        U8 pk;
        #pragma unroll
        for (int j = 0; j < 8; ++j) pk.us[j] = f2bf(vp[j * (NKV_ * D_)]);
        int slot = (d >> 4) * 64 + sc * 16 + (d & 15);
        *(bf16x8*)(base + 4096 + slot * 8) = pk.v;
    }
}

// ---------------- prep 2: per-row segment start indices ----------------
__global__ __launch_bounds__(256)
void prep_sstart(const int* __restrict__ seg, int* __restrict__ sstart)
{
    int idx = blockIdx.x * 256 + threadIdx.x;
    int b = idx >> 11, t = idx & (T_ - 1);
    const int* sb = seg + b * T_;
    int target = sb[t];
    int lo = 0, hi = t;
    while (lo < hi) { int mid = (lo + hi) >> 1; if (sb[mid] < target) lo = mid + 1; else hi = mid; }
    sstart[idx] = lo;
}

// ---------------- main attention kernel (no LDS, no barriers) ----------------
__global__ __launch_bounds__(256)
void attn_fwd(const float* __restrict__ qg,
              const int* __restrict__ sstart,
              const unsigned short* __restrict__ ws,
              float* __restrict__ outg)
{
    const int tid  = threadIdx.x;
    const int wave = tid >> 6;
    const int lane = tid & 63;
    const int qd   = lane >> 4;
    const int ln   = lane & 15;

    const int i    = blockIdx.x;             // 0..15 (folded pair index)
    const int head = blockIdx.y;
    const int kvh  = head >> 2;
    const int b    = blockIdx.z;

    const unsigned short* wsbase =
        ws + ((size_t)((b * NKV_ + kvh) * (T_ / 32))) * TILE_US + lane * 8;

    // load K(tile) and V(tile) fragments into named register buffers
#define LOADKV(KB, VB, tl) do {                                                \
        const unsigned short* _tb = wsbase + (size_t)(tl) * TILE_US;           \
        _Pragma("unroll")                                                      \
        for (int _c = 0; _c < 4; ++_c) {                                       \
            KB[_c][0] = *(const f16x8*)(_tb + (_c * 2 + 0) * 512);             \
            KB[_c][1] = *(const f16x8*)(_tb + (_c * 2 + 1) * 512);             \
        }                                                                      \
        _Pragma("unroll")                                                      \
        for (int _s = 0; _s < 8; ++_s)                                         \
            VB[_s] = *(const bf16x8*)(_tb + 4096 + _s * 512);                  \
    } while (0)

    // Swapped QK: S = mfma(Kfrag, Qfrag) -> lane(qd,ln) holds
    // S[kv = s0 + qd*4 + r (+16 for S1)][q-row = ln].  P transpose to the PV
    // A-operand layout (pa[k=qd*8+j] for q-row=ln) is 4 cvt_pk + 4 permlane swaps.
#define COMPUTE(KB, VB, TL) do {                                               \
        const int _s0 = (TL) * 32;                                             \
        f32x4 S0 = {0.f,0.f,0.f,0.f}, S1 = {0.f,0.f,0.f,0.f};                  \
        __builtin_amdgcn_s_setprio(1);                                         \
        _Pragma("unroll")                                                      \
        for (int c = 0; c < 4; ++c) {                                          \
            S0 = __builtin_amdgcn_mfma_f32_16x16x32_f16(KB[c][0], qh[c], S0,0,0,0); \
            S1 = __builtin_amdgcn_mfma_f32_16x16x32_f16(KB[c][1], qh[c], S1,0,0,0); \
            S0 = __builtin_amdgcn_mfma_f32_16x16x32_f16(KB[c][0], ql[c], S0,0,0,0); \
            S1 = __builtin_amdgcn_mfma_f32_16x16x32_f16(KB[c][1], ql[c], S1,0,0,0); \
        }                                                                      \
        __builtin_amdgcn_s_setprio(0);                                         \
        float p0[4], p1[4];                                                    \
        if (_s0 >= wave_rs_max && _s0 + 31 <= wave_row_min) {                  \
            _Pragma("unroll")                                                  \
            for (int r = 0; r < 4; ++r) {                                      \
                p0[r] = exp2f(S0[r]);                                          \
                p1[r] = exp2f(S1[r]);                                          \
            }                                                                  \
        } else {                                                               \
            _Pragma("unroll")                                                  \
            for (int r = 0; r < 4; ++r) {                                      \
                int kv0 = _s0 + qd * 4 + r;                                    \
                int kv1 = kv0 + 16;                                            \
                float sv0 = (kv0 >= rs_l && kv0 <= trow_l) ? S0[r] : MASKV;    \
                float sv1 = (kv1 >= rs_l && kv1 <= trow_l) ? S1[r] : MASKV;    \
                p0[r] = exp2f(sv0);                                            \
                p1[r] = exp2f(sv1);                                            \
            }                                                                  \
        }                                                                      \
        l_lane += (p0[0] + p0[1]) + (p0[2] + p0[3])                            \
                + (p1[0] + p1[1]) + (p1[2] + p1[3]);                           \
        PKW c0, c1, c2, c3;                                                    \
        c0.h = (bf16x2){(__bf16)p0[0], (__bf16)p0[1]};                         \
        c1.h = (bf16x2){(__bf16)p0[2], (__bf16)p0[3]};                         \
        c2.h = (bf16x2){(__bf16)p1[0], (__bf16)p1[1]};                         \
        c3.h = (bf16x2){(__bf16)p1[2], (__bf16)p1[3]};                         \
        unsigned int w0 = c0.u, w1 = c1.u, w2 = c2.u, w3 = c3.u;               \
        pl32swap(w0, w2); pl32swap(w1, w3);                                    \
        pl16swap(w0, w2); pl16swap(w1, w3);                                    \
        PA4 pw; pw.u[0] = w0; pw.u[1] = w1; pw.u[2] = w2; pw.u[3] = w3;        \
        bf16x8 pa = pw.v;                                                      \
        __builtin_amdgcn_s_setprio(1);                                         \
        _Pragma("unroll")                                                      \
        for (int sub = 0; sub < 8; ++sub)                                      \
            O[sub] = __builtin_amdgcn_mfma_f32_16x16x32_bf16(pa, VB[sub], O[sub],0,0,0); \
        __builtin_amdgcn_s_setprio(0);                                         \
    } while (0)

    // Folded pair: phase 0 = heavy Q-tile (2*gridDim.x-1-i), phase 1 = light (i).
    for (int phase = 0; phase < 2; ++phase) {
        const int t0 = (phase == 0 ? (2 * (int)gridDim.x - 1 - i) : i) * 64;

        // ---- preload Q fragments, scaled by log2(e), fp16 hi/lo split ----
        f16x8 qh[4], ql[4];
        {
            const float* qrow =
                qg + (((size_t)(b * T_ + (t0 + wave * 16 + ln)) * NQ_) + head) * D_;
            #pragma unroll
            for (int c = 0; c < 4; ++c) {
                float4 a  = *(const float4*)(qrow + c * 32 + qd * 8);
                float4 b2 = *(const float4*)(qrow + c * 32 + qd * 8 + 4);
                float xs[8] = {a.x, a.y, a.z, a.w, b2.x, b2.y, b2.z, b2.w};
                H8 hu, lu;
                #pragma unroll
                for (int j = 0; j < 8; ++j) {
                    float x = xs[j] * LOG2E;
                    _Float16 h = (_Float16)x;
                    hu.h[j] = h;
                    lu.h[j] = (_Float16)(x - (float)h);
                }
                qh[c] = hu.v; ql[c] = lu.v;
            }
        }

        // ---- per-lane row info (this lane's q-row is ln within the wave) ----
        const int trow_l = t0 + wave * 16 + ln;
        const int rs_l   = sstart[b * T_ + trow_l];
        int wave_rs_max = rs_l;
        wave_rs_max = max(wave_rs_max, __shfl_xor(wave_rs_max, 1));
        wave_rs_max = max(wave_rs_max, __shfl_xor(wave_rs_max, 2));
        wave_rs_max = max(wave_rs_max, __shfl_xor(wave_rs_max, 4));
        wave_rs_max = max(wave_rs_max, __shfl_xor(wave_rs_max, 8));
        const int wave_row_min = t0 + wave * 16;

        const int tile0   = sstart[b * T_ + t0] >> 5;       // block-uniform
        const int n_tiles = t0 / 32 + 2;

        f32x4 O[8];
        #pragma unroll
        for (int k = 0; k < 8; ++k) O[k] = (f32x4){0.f, 0.f, 0.f, 0.f};
        float l_lane = 0.f;      // softmax denom for q-row = ln (partial over this qd's kv slots)

        f16x8  kA[4][2], kB_[4][2];
        bf16x8 vA[8], vB_[8];

        int t = tile0;
        LOADKV(kA, vA, t);                      // prologue
        while (t + 1 < n_tiles) {
            LOADKV(kB_, vB_, t + 1);            // prefetch under compute(A)
            COMPUTE(kA, vA, t);
            if (t + 2 < n_tiles) LOADKV(kA, vA, t + 2);
            COMPUTE(kB_, vB_, t + 1);
            t += 2;
        }
        if (t < n_tiles) COMPUTE(kA, vA, t);

        // ---- epilogue: reduce l across qd groups, redistribute via shfl, store ----
        float l = l_lane;
        l += __shfl_xor(l, 16);
        l += __shfl_xor(l, 32);
        const float invl = 1.0f / l;           // per lane: denom for q-row = ln
        int trow[4];
        float inv[4];
        #pragma unroll
        for (int r = 0; r < 4; ++r) {
            trow[r] = t0 + wave * 16 + qd * 4 + r;
            inv[r]  = __shfl(invl, qd * 4 + r);   // lane (qd*4+r) holds denom for that row
        }
        #pragma unroll
        for (int sub = 0; sub < 8; ++sub) {
            #pragma unroll
            for (int r = 0; r < 4; ++r) {
                outg[(((size_t)(b * T_ + trow[r]) * NQ_) + head) * D_ + sub * 16 + ln] =
                    O[sub][r] * inv[r];
            }
        }
    }

#undef LOADKV
#undef COMPUTE
}

// ---------------- fallback (no-ws path) ----------------
#define KSTR 136
#define VSTR 40
#define PSTR 40
static __device__ __forceinline__ float bf2f(unsigned short h) {
    union { unsigned int u; float f; } c; c.u = (unsigned int)h << 16; return c.f;
}
__global__ __launch_bounds__(256)
void attn_fwd_fb(const float* __restrict__ qg,
                 const float* __restrict__ kg,
                 const float* __restrict__ vg,
                 const int* __restrict__ seg,
                 float* __restrict__ outg)
{
    __shared__ unsigned short sKh[32 * KSTR];
    __shared__ unsigned short sKl[32 * KSTR];
    __shared__ unsigned short sVt[128 * VSTR];
    __shared__ unsigned short sP[4][16 * PSTR];

    const int tid  = threadIdx.x;
    const int wave = tid >> 6;
    const int lane = tid & 63;
    const int qd   = lane >> 4;
    const int ln   = lane & 15;
    const int t0   = ((int)gridDim.x - 1 - (int)blockIdx.x) * 64;
    const int head = blockIdx.y;
    const int kvh  = head >> 2;
    const int b    = blockIdx.z;

    bf16x8 qh[4], ql[4];
    {
        const float* qrow =
            qg + (((size_t)(b * T_ + (t0 + wave * 16 + ln)) * NQ_) + head) * D_;
        #pragma unroll
        for (int c = 0; c < 4; ++c) {
            float4 a  = *(const float4*)(qrow + c * 32 + qd * 8);
            float4 b2 = *(const float4*)(qrow + c * 32 + qd * 8 + 4);
            float xs[8] = {a.x, a.y, a.z, a.w, b2.x, b2.y, b2.z, b2.w};
            U8 hu, lu;
            #pragma unroll
            for (int j = 0; j < 8; ++j) {
                unsigned short h = f2bf(xs[j]);
                hu.us[j] = h;
                lu.us[j] = f2bf(xs[j] - bf2f(h));
            }
            qh[c] = hu.v; ql[c] = lu.v;
        }
    }
    const int* sb = seg + (size_t)b * T_;
    int qseg[4];
    #pragma unroll
    for (int r = 0; r < 4; ++r) qseg[r] = sb[t0 + wave * 16 + qd * 4 + r];
    int tile0;
    {
        int target = sb[t0];
        int lo = 0, hi = t0;
        while (lo < hi) { int mid = (lo + hi) >> 1; if (sb[mid] < target) lo = mid + 1; else hi = mid; }
        tile0 = lo >> 5;
    }
    f32x4 O[8];
    #pragma unroll
    for (int i = 0; i < 8; ++i) O[i] = (f32x4){0.f, 0.f, 0.f, 0.f};
    float m_prev[4], l_lane[4];
    #pragma unroll
    for (int r = 0; r < 4; ++r) { m_prev[r] = MASKV; l_lane[r] = 0.f; }
    const int n_tiles = t0 / 32 + 2;

    for (int tile = tile0; tile < n_tiles; ++tile) {
        const int s0 = tile * 32;
        __syncthreads();
        #pragma unroll
        for (int it = 0; it < 2; ++it) {
            int task = tid + it * 256;
            int r = task >> 4, d = (task & 15) * 8;
            const float* kp = kg + (((size_t)(b * T_ + s0 + r) * NKV_) + kvh) * D_ + d;
            float4 a  = *(const float4*)(kp);
            float4 b2 = *(const float4*)(kp + 4);
            float xs[8] = {a.x, a.y, a.z, a.w, b2.x, b2.y, b2.z, b2.w};
            U8 hu, lu;
            #pragma unroll
            for (int j = 0; j < 8; ++j) {
                unsigned short h = f2bf(xs[j]);
                hu.us[j] = h;
                lu.us[j] = f2bf(xs[j] - bf2f(h));
            }
            *(bf16x8*)(sKh + r * KSTR + d) = hu.v;
            *(bf16x8*)(sKl + r * KSTR + d) = lu.v;
        }
        #pragma unroll
        for (int it = 0; it < 2; ++it) {
            int task = tid + it * 256;
            int d = task & 127, sg = task >> 7;
            const float* vp = vg + (((size_t)(b * T_ + s0 + sg * 8) * NKV_) + kvh) * D_ + d;
            U8 pk;
            #pragma unroll
            for (int j = 0; j < 8; ++j) pk.us[j] = f2bf(vp[j * (NKV_ * D_)]);
            *(bf16x8*)(sVt + d * VSTR + sg * 8) = pk.v;
        }
        __syncthreads();

        f32x4 S0 = {0.f,0.f,0.f,0.f}, S1 = {0.f,0.f,0.f,0.f};
        #pragma unroll
        for (int c = 0; c < 4; ++c) {
            bf16x8 kh0 = *(const bf16x8*)(sKh + ln * KSTR + c * 32 + qd * 8);
            bf16x8 kh1 = *(const bf16x8*)(sKh + (16 + ln) * KSTR + c * 32 + qd * 8);
            bf16x8 kl0 = *(const bf16x8*)(sKl + ln * KSTR + c * 32 + qd * 8);
            bf16x8 kl1 = *(const bf16x8*)(sKl + (16 + ln) * KSTR + c * 32 + qd * 8);
            S0 = __builtin_amdgcn_mfma_f32_16x16x32_bf16(qh[c], kh0, S0, 0, 0, 0);
            S1 = __builtin_amdgcn_mfma_f32_16x16x32_bf16(qh[c], kh1, S1, 0, 0, 0);
            S0 = __builtin_amdgcn_mfma_f32_16x16x32_bf16(qh[c], kl0, S0, 0, 0, 0);
            S1 = __builtin_amdgcn_mfma_f32_16x16x32_bf16(qh[c], kl1, S1, 0, 0, 0);
            S0 = __builtin_amdgcn_mfma_f32_16x16x32_bf16(ql[c], kh0, S0, 0, 0, 0);
            S1 = __builtin_amdgcn_mfma_f32_16x16x32_bf16(ql[c], kh1, S1, 0, 0, 0);
        }
        const int ks0 = sb[s0 + ln];
        const int ks1 = sb[s0 + 16 + ln];
        float p0[4], p1[4], alpha[4];
        #pragma unroll
        for (int r = 0; r < 4; ++r) {
            const int trow = t0 + wave * 16 + qd * 4 + r;
            float s0v = ((s0 + ln <= trow) && (ks0 == qseg[r])) ? S0[r] : MASKV;
            float s1v = ((s0 + 16 + ln <= trow) && (ks1 == qseg[r])) ? S1[r] : MASKV;
            float mx = fmaxf(s0v, s1v);
            mx = fmaxf(mx, __shfl_xor(mx, 1));
            mx = fmaxf(mx, __shfl_xor(mx, 2));
            mx = fmaxf(mx, __shfl_xor(mx, 4));
            mx = fmaxf(mx, __shfl_xor(mx, 8));
            const float mn = fmaxf(m_prev[r], mx);
            alpha[r] = __expf(m_prev[r] - mn);
            p0[r] = __expf(s0v - mn);
            p1[r] = __expf(s1v - mn);
            l_lane[r] = alpha[r] * l_lane[r] + p0[r] + p1[r];
            m_prev[r] = mn;
        }
        #pragma unroll
        for (int i = 0; i < 8; ++i) {
            O[i][0] *= alpha[0]; O[i][1] *= alpha[1];
            O[i][2] *= alpha[2]; O[i][3] *= alpha[3];
        }
        {
            unsigned short* pw = sP[wave] + (qd * 4) * PSTR + ln;
            #pragma unroll
            for (int r = 0; r < 4; ++r) {
                pw[r * PSTR]      = f2bf(p0[r]);
                pw[r * PSTR + 16] = f2bf(p1[r]);
            }
        }
        asm volatile("s_waitcnt lgkmcnt(0)" ::: "memory");
        bf16x8 pa = *(const bf16x8*)(sP[wave] + ln * PSTR + qd * 8);
        #pragma unroll
        for (int sub = 0; sub < 8; ++sub) {
            bf16x8 bv = *(const bf16x8*)(sVt + (sub * 16 + ln) * VSTR + qd * 8);
            O[sub] = __builtin_amdgcn_mfma_f32_16x16x32_bf16(pa, bv, O[sub], 0, 0, 0);
        }
    }
    float inv[4];
    #pragma unroll
    for (int r = 0; r < 4; ++r) {
        float l = l_lane[r];
        l += __shfl_xor(l, 1);
        l += __shfl_xor(l, 2);
        l += __shfl_xor(l, 4);
        l += __shfl_xor(l, 8);
        inv[r] = 1.0f / l;
    }
    #pragma unroll
    for (int sub = 0; sub < 8; ++sub) {
        #pragma unroll
        for (int r = 0; r < 4; ++r) {
            const int trow = t0 + wave * 16 + qd * 4 + r;
            outg[(((size_t)(b * T_ + trow) * NQ_) + head) * D_ + sub * 16 + ln] =
                O[sub][r] * inv[r];
        }
    }
}

extern "C" void kernel_launch(void* const* d_in, const int* in_sizes, int n_in,
                              void* d_out, int out_size, void* d_ws, size_t ws_size,
                              hipStream_t stream) {
    const float* q  = (const float*)d_in[0];
    const float* k  = (const float*)d_in[1];
    const float* v  = (const float*)d_in[2];
    const int*   sg = (const int*)d_in[3];
    float*       o  = (float*)d_out;
    if (ws_size >= WS_NEED) {
        unsigned short* ws = (unsigned short*)d_ws;
        int* sstart = (int*)((char*)d_ws + WS_TILES_BYTES);
        prep<<<dim3(T_ / 32, NKV_, B_), dim3(256), 0, stream>>>(k, v, ws);
        prep_sstart<<<dim3(B_ * T_ / 256), dim3(256), 0, stream>>>(sg, sstart);
        attn_fwd<<<dim3(T_ / 128, NQ_, B_), dim3(256), 0, stream>>>(q, sstart, ws, o);
    } else {
        attn_fwd_fb<<<dim3(T_ / 64, NQ_, B_), dim3(256), 0, stream>>>(q, k, v, sg, o);
    }
}

// Round 5
// 198.592 us; speedup vs baseline: 1.1297x; 1.1297x over previous
//
#include <hip/hip_runtime.h>

// GQA causal+segment-masked flash attention. fp32 in/out.
// B=2, T=2048, NQ=32 (8 kv heads x 4), D=128.
// R12: TLP round. 1-wave workgroups (64 threads, 16 q-rows each), grid
// (32 heads, 64 folded chunk-pairs, 2) = 4096 independent waves -> 4
// waves/SIMD co-resident (R9-R11 showed ~1 effective wave/SIMD; the
// per-tile latency chain was naked: invariant ~900cyc/tile across 3
// structurally different kernels). No LDS, no barriers, register-loaded
// KV from prepped ws (R11). Keeps: swapped QK mfma(K,Q), in-register P
// transpose (cvt_pk_bf16 + permlane16/32_swap), unnormalized exp2 accum,
// folded causal pairing (uniform wave duration), setprio around MFMA.

typedef __bf16 bf16x8 __attribute__((ext_vector_type(8)));
typedef __bf16 bf16x2 __attribute__((ext_vector_type(2)));
typedef _Float16 f16x8 __attribute__((ext_vector_type(8)));
typedef float f32x4 __attribute__((ext_vector_type(4)));
typedef unsigned int uint2v __attribute__((ext_vector_type(2)));

#define B_   2
#define T_   2048
#define NQ_  32
#define NKV_ 8
#define D_   128

#define MASKV (-3.0e38f)
#define LOG2E 1.44269504f
#define TILE_US 8192           // ushorts per 32-col KV tile in ws: 8KB fp16 K + 8KB bf16 Vt
#define WS_TILES_BYTES ((size_t)B_ * NKV_ * (T_ / 32) * TILE_US * 2)   // 16777216
#define WS_NEED (WS_TILES_BYTES + (size_t)B_ * T_ * 4)

static __device__ __forceinline__ unsigned short f2bf(float x) {
    union { float f; unsigned int u; } c; c.f = x;
    unsigned int r = c.u + 0x7fffu + ((c.u >> 16) & 1u);
    return (unsigned short)(r >> 16);
}

union U8  { unsigned short us[8]; bf16x8 v; };
union H8  { _Float16 h[8]; f16x8 v; };
union PKW { bf16x2 h; unsigned int u; };
union PA4 { unsigned int u[4]; bf16x8 v; };

// register-pair lane swaps (gfx950): a[32:63] <-> b[0:31]  /  a[16:31]<->b[0:15], a[48:63]<->b[32:47]
static __device__ __forceinline__ void pl32swap(unsigned int& a, unsigned int& b) {
#if __has_builtin(__builtin_amdgcn_permlane32_swap)
    uint2v t = __builtin_amdgcn_permlane32_swap(a, b, false, false);
    a = t.x; b = t.y;
#else
    asm("s_nop 1\n\tv_permlane32_swap_b32 %0, %1" : "+v"(a), "+v"(b));
#endif
}
static __device__ __forceinline__ void pl16swap(unsigned int& a, unsigned int& b) {
#if __has_builtin(__builtin_amdgcn_permlane16_swap)
    uint2v t = __builtin_amdgcn_permlane16_swap(a, b, false, false);
    a = t.x; b = t.y;
#else
    asm("s_nop 1\n\tv_permlane16_swap_b32 %0, %1" : "+v"(a), "+v"(b));
#endif
}

// ---------------- prep 1: K -> fp16, V^T -> bf16, fragment-ordered ws tiles ----------------
// K region (ushort 0..4095):  16B slot = (c*2+hi)*64 + qd*16 + ln
//   holds K[row = hi*16+ln][d = c*32+qd*8 .. +7] as fp16.
//   -> wave load instr (c,hi): 64 lanes read contiguous 1KB at (c*2+hi)*512.
// V region (ushort 4096..8191): 16B slot = sub*64 + sc*16 + dln
//   holds V^T[d = sub*16+dln][kv = sc*8 .. +7] as bf16.
//   -> wave load instr (sub): contiguous 1KB at 4096 + sub*512.
__global__ __launch_bounds__(256)
void prep(const float* __restrict__ kg, const float* __restrict__ vg,
          unsigned short* __restrict__ ws)
{
    const int tid = threadIdx.x;
    const int st  = blockIdx.x;    // 32-col KV tile index
    const int kvh = blockIdx.y;
    const int b   = blockIdx.z;
    unsigned short* base = ws + ((size_t)((b * NKV_ + kvh) * (T_ / 32) + st)) * TILE_US;

    // K: 512 tasks = 32 rows x 16 chunks(8 elems), fp16
    #pragma unroll
    for (int it = 0; it < 2; ++it) {
        int task = tid + it * 256;
        int r = task >> 4, c16 = task & 15;            // d = c16*8
        const float* kp = kg + (((size_t)(b * T_ + st * 32 + r)) * NKV_ + kvh) * D_ + c16 * 8;
        H8 hu;
        #pragma unroll
        for (int j = 0; j < 8; ++j) hu.h[j] = (_Float16)kp[j];
        int c = c16 >> 2, qd = c16 & 3, hi = r >> 4, ln = r & 15;
        int slot = (c * 2 + hi) * 64 + qd * 16 + ln;
        *(f16x8*)(base + slot * 8) = hu.v;
    }
    // V^T: 512 tasks = 128 d x 4 s-chunks(8 s), bf16
    #pragma unroll
    for (int it = 0; it < 2; ++it) {
        int task = tid + it * 256;
        int d = task & 127, sc = task >> 7;
        const float* vp = vg + (((size_t)(b * T_ + st * 32 + sc * 8)) * NKV_ + kvh) * D_ + d;
        U8 pk;
        #pragma unroll
        for (int j = 0; j < 8; ++j) pk.us[j] = f2bf(vp[j * (NKV_ * D_)]);
        int slot = (d >> 4) * 64 + sc * 16 + (d & 15);
        *(bf16x8*)(base + 4096 + slot * 8) = pk.v;
    }
}

// ---------------- prep 2: per-row segment start indices ----------------
__global__ __launch_bounds__(256)
void prep_sstart(const int* __restrict__ seg, int* __restrict__ sstart)
{
    int idx = blockIdx.x * 256 + threadIdx.x;
    int b = idx >> 11, t = idx & (T_ - 1);
    const int* sb = seg + b * T_;
    int target = sb[t];
    int lo = 0, hi = t;
    while (lo < hi) { int mid = (lo + hi) >> 1; if (sb[mid] < target) lo = mid + 1; else hi = mid; }
    sstart[idx] = lo;
}

// ---------------- main attention kernel (1 wave per block, no LDS, no barriers) ----------------
__global__ __launch_bounds__(64)
void attn_fwd(const float* __restrict__ qg,
              const int* __restrict__ sstart,
              const unsigned short* __restrict__ ws,
              float* __restrict__ outg)
{
    const int lane = threadIdx.x & 63;
    const int qd   = lane >> 4;
    const int ln   = lane & 15;

    const int head = blockIdx.x;             // head-fastest: same-kvh blocks adjacent
    const int j    = blockIdx.y;             // folded chunk-pair index 0..63
    const int kvh  = head >> 2;
    const int b    = blockIdx.z;

    const unsigned short* wsbase =
        ws + ((size_t)((b * NKV_ + kvh) * (T_ / 32))) * TILE_US + lane * 8;

    // load K(tile) and V(tile) fragments into named register buffers
#define LOADKV(KB, VB, tl) do {                                                \
        const unsigned short* _tb = wsbase + (size_t)(tl) * TILE_US;           \
        _Pragma("unroll")                                                      \
        for (int _c = 0; _c < 4; ++_c) {                                       \
            KB[_c][0] = *(const f16x8*)(_tb + (_c * 2 + 0) * 512);             \
            KB[_c][1] = *(const f16x8*)(_tb + (_c * 2 + 1) * 512);             \
        }                                                                      \
        _Pragma("unroll")                                                      \
        for (int _s = 0; _s < 8; ++_s)                                         \
            VB[_s] = *(const bf16x8*)(_tb + 4096 + _s * 512);                  \
    } while (0)

    // Swapped QK: S = mfma(Kfrag, Qfrag) -> lane(qd,ln) holds
    // S[kv = s0 + qd*4 + r (+16 for S1)][q-row = ln].  P transpose to the PV
    // A-operand layout (pa[k=qd*8+j] for q-row=ln) is 4 cvt_pk + 4 permlane swaps.
#define COMPUTE(KB, VB, TL) do {                                               \
        const int _s0 = (TL) * 32;                                             \
        f32x4 S0 = {0.f,0.f,0.f,0.f}, S1 = {0.f,0.f,0.f,0.f};                  \
        __builtin_amdgcn_s_setprio(1);                                         \
        _Pragma("unroll")                                                      \
        for (int c = 0; c < 4; ++c) {                                          \
            S0 = __builtin_amdgcn_mfma_f32_16x16x32_f16(KB[c][0], qh[c], S0,0,0,0); \
            S1 = __builtin_amdgcn_mfma_f32_16x16x32_f16(KB[c][1], qh[c], S1,0,0,0); \
            S0 = __builtin_amdgcn_mfma_f32_16x16x32_f16(KB[c][0], ql[c], S0,0,0,0); \
            S1 = __builtin_amdgcn_mfma_f32_16x16x32_f16(KB[c][1], ql[c], S1,0,0,0); \
        }                                                                      \
        __builtin_amdgcn_s_setprio(0);                                         \
        float p0[4], p1[4];                                                    \
        if (_s0 >= wave_rs_max && _s0 + 31 <= wave_row_min) {                  \
            _Pragma("unroll")                                                  \
            for (int r = 0; r < 4; ++r) {                                      \
                p0[r] = exp2f(S0[r]);                                          \
                p1[r] = exp2f(S1[r]);                                          \
            }                                                                  \
        } else {                                                               \
            _Pragma("unroll")                                                  \
            for (int r = 0; r < 4; ++r) {                                      \
                int kv0 = _s0 + qd * 4 + r;                                    \
                int kv1 = kv0 + 16;                                            \
                float sv0 = (kv0 >= rs_l && kv0 <= trow_l) ? S0[r] : MASKV;    \
                float sv1 = (kv1 >= rs_l && kv1 <= trow_l) ? S1[r] : MASKV;    \
                p0[r] = exp2f(sv0);                                            \
                p1[r] = exp2f(sv1);                                            \
            }                                                                  \
        }                                                                      \
        l_lane += (p0[0] + p0[1]) + (p0[2] + p0[3])                            \
                + (p1[0] + p1[1]) + (p1[2] + p1[3]);                           \
        PKW c0, c1, c2, c3;                                                    \
        c0.h = (bf16x2){(__bf16)p0[0], (__bf16)p0[1]};                         \
        c1.h = (bf16x2){(__bf16)p0[2], (__bf16)p0[3]};                         \
        c2.h = (bf16x2){(__bf16)p1[0], (__bf16)p1[1]};                         \
        c3.h = (bf16x2){(__bf16)p1[2], (__bf16)p1[3]};                         \
        unsigned int w0 = c0.u, w1 = c1.u, w2 = c2.u, w3 = c3.u;               \
        pl32swap(w0, w2); pl32swap(w1, w3);                                    \
        pl16swap(w0, w2); pl16swap(w1, w3);                                    \
        PA4 pw; pw.u[0] = w0; pw.u[1] = w1; pw.u[2] = w2; pw.u[3] = w3;        \
        bf16x8 pa = pw.v;                                                      \
        __builtin_amdgcn_s_setprio(1);                                         \
        _Pragma("unroll")                                                      \
        for (int sub = 0; sub < 8; ++sub)                                      \
            O[sub] = __builtin_amdgcn_mfma_f32_16x16x32_bf16(pa, VB[sub], O[sub],0,0,0); \
        __builtin_amdgcn_s_setprio(0);                                         \
    } while (0)

    // Folded pair: phase 0 = heavy 16-row chunk (127-j), phase 1 = light (j).
    for (int phase = 0; phase < 2; ++phase) {
        const int chunk = (phase == 0) ? (2 * (int)gridDim.y - 1 - j) : j;
        const int t0 = chunk * 16;

        // ---- preload Q fragments, scaled by log2(e), fp16 hi/lo split ----
        f16x8 qh[4], ql[4];
        {
            const float* qrow =
                qg + (((size_t)(b * T_ + (t0 + ln)) * NQ_) + head) * D_;
            #pragma unroll
            for (int c = 0; c < 4; ++c) {
                float4 a  = *(const float4*)(qrow + c * 32 + qd * 8);
                float4 b2 = *(const float4*)(qrow + c * 32 + qd * 8 + 4);
                float xs[8] = {a.x, a.y, a.z, a.w, b2.x, b2.y, b2.z, b2.w};
                H8 hu, lu;
                #pragma unroll
                for (int jj = 0; jj < 8; ++jj) {
                    float x = xs[jj] * LOG2E;
                    _Float16 h = (_Float16)x;
                    hu.h[jj] = h;
                    lu.h[jj] = (_Float16)(x - (float)h);
                }
                qh[c] = hu.v; ql[c] = lu.v;
            }
        }

        // ---- per-lane row info (this lane's q-row is ln within the wave) ----
        const int trow_l = t0 + ln;
        const int rs_l   = sstart[b * T_ + trow_l];
        const int wave_rs_max  = sstart[b * T_ + t0 + 15];   // sorted -> max of the 16 rows
        const int wave_row_min = t0;

        const int tile0   = sstart[b * T_ + t0] >> 5;        // wave-uniform
        const int n_tiles = ((t0 + 15) >> 5) + 1;

        f32x4 O[8];
        #pragma unroll
        for (int k = 0; k < 8; ++k) O[k] = (f32x4){0.f, 0.f, 0.f, 0.f};
        float l_lane = 0.f;      // softmax denom for q-row = ln (partial over this qd's kv slots)

        f16x8  kA[4][2], kB_[4][2];
        bf16x8 vA[8], vB_[8];

        int t = tile0;
        LOADKV(kA, vA, t);                      // prologue
        while (t + 1 < n_tiles) {
            LOADKV(kB_, vB_, t + 1);            // prefetch under compute(A)
            COMPUTE(kA, vA, t);
            if (t + 2 < n_tiles) LOADKV(kA, vA, t + 2);
            COMPUTE(kB_, vB_, t + 1);
            t += 2;
        }
        if (t < n_tiles) COMPUTE(kA, vA, t);

        // ---- epilogue: reduce l across qd groups, redistribute via shfl, store ----
        float l = l_lane;
        l += __shfl_xor(l, 16);
        l += __shfl_xor(l, 32);
        const float invl = 1.0f / l;           // per lane: denom for q-row = ln
        int trow[4];
        float inv[4];
        #pragma unroll
        for (int r = 0; r < 4; ++r) {
            trow[r] = t0 + qd * 4 + r;
            inv[r]  = __shfl(invl, qd * 4 + r);   // lane (qd*4+r) holds denom for that row
        }
        #pragma unroll
        for (int sub = 0; sub < 8; ++sub) {
            #pragma unroll
            for (int r = 0; r < 4; ++r) {
                outg[(((size_t)(b * T_ + trow[r]) * NQ_) + head) * D_ + sub * 16 + ln] =
                    O[sub][r] * inv[r];
            }
        }
    }

#undef LOADKV
#undef COMPUTE
}

// ---------------- fallback (no-ws path) ----------------
#define KSTR 136
#define VSTR 40
#define PSTR 40
static __device__ __forceinline__ float bf2f(unsigned short h) {
    union { unsigned int u; float f; } c; c.u = (unsigned int)h << 16; return c.f;
}
__global__ __launch_bounds__(256)
void attn_fwd_fb(const float* __restrict__ qg,
                 const float* __restrict__ kg,
                 const float* __restrict__ vg,
                 const int* __restrict__ seg,
                 float* __restrict__ outg)
{
    __shared__ unsigned short sKh[32 * KSTR];
    __shared__ unsigned short sKl[32 * KSTR];
    __shared__ unsigned short sVt[128 * VSTR];
    __shared__ unsigned short sP[4][16 * PSTR];

    const int tid  = threadIdx.x;
    const int wave = tid >> 6;
    const int lane = tid & 63;
    const int qd   = lane >> 4;
    const int ln   = lane & 15;
    const int t0   = ((int)gridDim.x - 1 - (int)blockIdx.x) * 64;
    const int head = blockIdx.y;
    const int kvh  = head >> 2;
    const int b    = blockIdx.z;

    bf16x8 qh[4], ql[4];
    {
        const float* qrow =
            qg + (((size_t)(b * T_ + (t0 + wave * 16 + ln)) * NQ_) + head) * D_;
        #pragma unroll
        for (int c = 0; c < 4; ++c) {
            float4 a  = *(const float4*)(qrow + c * 32 + qd * 8);
            float4 b2 = *(const float4*)(qrow + c * 32 + qd * 8 + 4);
            float xs[8] = {a.x, a.y, a.z, a.w, b2.x, b2.y, b2.z, b2.w};
            U8 hu, lu;
            #pragma unroll
            for (int j = 0; j < 8; ++j) {
                unsigned short h = f2bf(xs[j]);
                hu.us[j] = h;
                lu.us[j] = f2bf(xs[j] - bf2f(h));
            }
            qh[c] = hu.v; ql[c] = lu.v;
        }
    }
    const int* sb = seg + (size_t)b * T_;
    int qseg[4];
    #pragma unroll
    for (int r = 0; r < 4; ++r) qseg[r] = sb[t0 + wave * 16 + qd * 4 + r];
    int tile0;
    {
        int target = sb[t0];
        int lo = 0, hi = t0;
        while (lo < hi) { int mid = (lo + hi) >> 1; if (sb[mid] < target) lo = mid + 1; else hi = mid; }
        tile0 = lo >> 5;
    }
    f32x4 O[8];
    #pragma unroll
    for (int i = 0; i < 8; ++i) O[i] = (f32x4){0.f, 0.f, 0.f, 0.f};
    float m_prev[4], l_lane[4];
    #pragma unroll
    for (int r = 0; r < 4; ++r) { m_prev[r] = MASKV; l_lane[r] = 0.f; }
    const int n_tiles = t0 / 32 + 2;

    for (int tile = tile0; tile < n_tiles; ++tile) {
        const int s0 = tile * 32;
        __syncthreads();
        #pragma unroll
        for (int it = 0; it < 2; ++it) {
            int task = tid + it * 256;
            int r = task >> 4, d = (task & 15) * 8;
            const float* kp = kg + (((size_t)(b * T_ + s0 + r) * NKV_) + kvh) * D_ + d;
            float4 a  = *(const float4*)(kp);
            float4 b2 = *(const float4*)(kp + 4);
            float xs[8] = {a.x, a.y, a.z, a.w, b2.x, b2.y, b2.z, b2.w};
            U8 hu, lu;
            #pragma unroll
            for (int j = 0; j < 8; ++j) {
                unsigned short h = f2bf(xs[j]);
                hu.us[j] = h;
                lu.us[j] = f2bf(xs[j] - bf2f(h));
            }
            *(bf16x8*)(sKh + r * KSTR + d) = hu.v;
            *(bf16x8*)(sKl + r * KSTR + d) = lu.v;
        }
        #pragma unroll
        for (int it = 0; it < 2; ++it) {
            int task = tid + it * 256;
            int d = task & 127, sg = task >> 7;
            const float* vp = vg + (((size_t)(b * T_ + s0 + sg * 8) * NKV_) + kvh) * D_ + d;
            U8 pk;
            #pragma unroll
            for (int j = 0; j < 8; ++j) pk.us[j] = f2bf(vp[j * (NKV_ * D_)]);
            *(bf16x8*)(sVt + d * VSTR + sg * 8) = pk.v;
        }
        __syncthreads();

        f32x4 S0 = {0.f,0.f,0.f,0.f}, S1 = {0.f,0.f,0.f,0.f};
        #pragma unroll
        for (int c = 0; c < 4; ++c) {
            bf16x8 kh0 = *(const bf16x8*)(sKh + ln * KSTR + c * 32 + qd * 8);
            bf16x8 kh1 = *(const bf16x8*)(sKh + (16 + ln) * KSTR + c * 32 + qd * 8);
            bf16x8 kl0 = *(const bf16x8*)(sKl + ln * KSTR + c * 32 + qd * 8);
            bf16x8 kl1 = *(const bf16x8*)(sKl + (16 + ln) * KSTR + c * 32 + qd * 8);
            S0 = __builtin_amdgcn_mfma_f32_16x16x32_bf16(qh[c], kh0, S0, 0, 0, 0);
            S1 = __builtin_amdgcn_mfma_f32_16x16x32_bf16(qh[c], kh1, S1, 0, 0, 0);
            S0 = __builtin_amdgcn_mfma_f32_16x16x32_bf16(qh[c], kl0, S0, 0, 0, 0);
            S1 = __builtin_amdgcn_mfma_f32_16x16x32_bf16(qh[c], kl1, S1, 0, 0, 0);
            S0 = __builtin_amdgcn_mfma_f32_16x16x32_bf16(ql[c], kh0, S0, 0, 0, 0);
            S1 = __builtin_amdgcn_mfma_f32_16x16x32_bf16(ql[c], kh1, S1, 0, 0, 0);
        }
        const int ks0 = sb[s0 + ln];
        const int ks1 = sb[s0 + 16 + ln];
        float p0[4], p1[4], alpha[4];
        #pragma unroll
        for (int r = 0; r < 4; ++r) {
            const int trow = t0 + wave * 16 + qd * 4 + r;
            float s0v = ((s0 + ln <= trow) && (ks0 == qseg[r])) ? S0[r] : MASKV;
            float s1v = ((s0 + 16 + ln <= trow) && (ks1 == qseg[r])) ? S1[r] : MASKV;
            float mx = fmaxf(s0v, s1v);
            mx = fmaxf(mx, __shfl_xor(mx, 1));
            mx = fmaxf(mx, __shfl_xor(mx, 2));
            mx = fmaxf(mx, __shfl_xor(mx, 4));
            mx = fmaxf(mx, __shfl_xor(mx, 8));
            const float mn = fmaxf(m_prev[r], mx);
            alpha[r] = __expf(m_prev[r] - mn);
            p0[r] = __expf(s0v - mn);
            p1[r] = __expf(s1v - mn);
            l_lane[r] = alpha[r] * l_lane[r] + p0[r] + p1[r];
            m_prev[r] = mn;
        }
        #pragma unroll
        for (int i = 0; i < 8; ++i) {
            O[i][0] *= alpha[0]; O[i][1] *= alpha[1];
            O[i][2] *= alpha[2]; O[i][3] *= alpha[3];
        }
        {
            unsigned short* pw = sP[wave] + (qd * 4) * PSTR + ln;
            #pragma unroll
            for (int r = 0; r < 4; ++r) {
                pw[r * PSTR]      = f2bf(p0[r]);
                pw[r * PSTR + 16] = f2bf(p1[r]);
            }
        }
        asm volatile("s_waitcnt lgkmcnt(0)" ::: "memory");
        bf16x8 pa = *(const bf16x8*)(sP[wave] + ln * PSTR + qd * 8);
        #pragma unroll
        for (int sub = 0; sub < 8; ++sub) {
            bf16x8 bv = *(const bf16x8*)(sVt + (sub * 16 + ln) * VSTR + qd * 8);
            O[sub] = __builtin_amdgcn_mfma_f32_16x16x32_bf16(pa, bv, O[sub], 0, 0, 0);
        }
    }
    float inv[4];
    #pragma unroll
    for (int r = 0; r < 4; ++r) {
        float l = l_lane[r];
        l += __shfl_xor(l, 1);
        l += __shfl_xor(l, 2);
        l += __shfl_xor(l, 4);
        l += __shfl_xor(l, 8);
        inv[r] = 1.0f / l;
    }
    #pragma unroll
    for (int sub = 0; sub < 8; ++sub) {
        #pragma unroll
        for (int r = 0; r < 4; ++r) {
            const int trow = t0 + wave * 16 + qd * 4 + r;
            outg[(((size_t)(b * T_ + trow) * NQ_) + head) * D_ + sub * 16 + ln] =
                O[sub][r] * inv[r];
        }
    }
}

extern "C" void kernel_launch(void* const* d_in, const int* in_sizes, int n_in,
                              void* d_out, int out_size, void* d_ws, size_t ws_size,
                              hipStream_t stream) {
    const float* q  = (const float*)d_in[0];
    const float* k  = (const float*)d_in[1];
    const float* v  = (const float*)d_in[2];
    const int*   sg = (const int*)d_in[3];
    float*       o  = (float*)d_out;
    if (ws_size >= WS_NEED) {
        unsigned short* ws = (unsigned short*)d_ws;
        int* sstart = (int*)((char*)d_ws + WS_TILES_BYTES);
        prep<<<dim3(T_ / 32, NKV_, B_), dim3(256), 0, stream>>>(k, v, ws);
        prep_sstart<<<dim3(B_ * T_ / 256), dim3(256), 0, stream>>>(sg, sstart);
        attn_fwd<<<dim3(NQ_, T_ / 32, B_), dim3(64), 0, stream>>>(q, sstart, ws, o);
    } else {
        attn_fwd_fb<<<dim3(T_ / 64, NQ_, B_), dim3(256), 0, stream>>>(q, k, v, sg, o);
    }
}

// Round 6
// 193.484 us; speedup vs baseline: 1.1595x; 1.0264x over previous
//
#include <hip/hip_runtime.h>

// GQA causal+segment-masked flash attention. fp32 in/out.
// B=2, T=2048, NQ=32 (8 kv heads x 4), D=128.
// R13: R12 per-wave code, but 4 INDEPENDENT waves packed per 256-thread
// workgroup (no barriers, no LDS): wave w = head kvh*4+w, same folded
// chunk-pair j. R12 showed concurrency capped at ~5.6 waves/CU (82.7us,
// 17% occ) with 4096 single-wave workgroups -> SPI launch/slot rate for
// tiny workgroups is the limiter, not VGPR/LDS. 1024 workgroups = 4/CU
// = 16 waves/CU resident; the 4 waves also share the same KV tile
// stream (same kvh,j) -> L1 broadcast. Keeps: swapped QK mfma(K,Q),
// in-register P transpose (cvt_pk_bf16 + permlane16/32_swap),
// unnormalized exp2 accum, folded causal pairing, setprio.

typedef __bf16 bf16x8 __attribute__((ext_vector_type(8)));
typedef __bf16 bf16x2 __attribute__((ext_vector_type(2)));
typedef _Float16 f16x8 __attribute__((ext_vector_type(8)));
typedef float f32x4 __attribute__((ext_vector_type(4)));
typedef unsigned int uint2v __attribute__((ext_vector_type(2)));

#define B_   2
#define T_   2048
#define NQ_  32
#define NKV_ 8
#define D_   128

#define MASKV (-3.0e38f)
#define LOG2E 1.44269504f
#define TILE_US 8192           // ushorts per 32-col KV tile in ws: 8KB fp16 K + 8KB bf16 Vt
#define WS_TILES_BYTES ((size_t)B_ * NKV_ * (T_ / 32) * TILE_US * 2)   // 16777216
#define WS_NEED (WS_TILES_BYTES + (size_t)B_ * T_ * 4)

static __device__ __forceinline__ unsigned short f2bf(float x) {
    union { float f; unsigned int u; } c; c.f = x;
    unsigned int r = c.u + 0x7fffu + ((c.u >> 16) & 1u);
    return (unsigned short)(r >> 16);
}

union U8  { unsigned short us[8]; bf16x8 v; };
union H8  { _Float16 h[8]; f16x8 v; };
union PKW { bf16x2 h; unsigned int u; };
union PA4 { unsigned int u[4]; bf16x8 v; };

// register-pair lane swaps (gfx950): a[32:63] <-> b[0:31]  /  a[16:31]<->b[0:15], a[48:63]<->b[32:47]
static __device__ __forceinline__ void pl32swap(unsigned int& a, unsigned int& b) {
#if __has_builtin(__builtin_amdgcn_permlane32_swap)
    uint2v t = __builtin_amdgcn_permlane32_swap(a, b, false, false);
    a = t.x; b = t.y;
#else
    asm("s_nop 1\n\tv_permlane32_swap_b32 %0, %1" : "+v"(a), "+v"(b));
#endif
}
static __device__ __forceinline__ void pl16swap(unsigned int& a, unsigned int& b) {
#if __has_builtin(__builtin_amdgcn_permlane16_swap)
    uint2v t = __builtin_amdgcn_permlane16_swap(a, b, false, false);
    a = t.x; b = t.y;
#else
    asm("s_nop 1\n\tv_permlane16_swap_b32 %0, %1" : "+v"(a), "+v"(b));
#endif
}

// ---------------- prep 1: K -> fp16, V^T -> bf16, fragment-ordered ws tiles ----------------
// K region (ushort 0..4095):  16B slot = (c*2+hi)*64 + qd*16 + ln
//   holds K[row = hi*16+ln][d = c*32+qd*8 .. +7] as fp16.
//   -> wave load instr (c,hi): 64 lanes read contiguous 1KB at (c*2+hi)*512.
// V region (ushort 4096..8191): 16B slot = sub*64 + sc*16 + dln
//   holds V^T[d = sub*16+dln][kv = sc*8 .. +7] as bf16.
//   -> wave load instr (sub): contiguous 1KB at 4096 + sub*512.
__global__ __launch_bounds__(256)
void prep(const float* __restrict__ kg, const float* __restrict__ vg,
          unsigned short* __restrict__ ws)
{
    const int tid = threadIdx.x;
    const int st  = blockIdx.x;    // 32-col KV tile index
    const int kvh = blockIdx.y;
    const int b   = blockIdx.z;
    unsigned short* base = ws + ((size_t)((b * NKV_ + kvh) * (T_ / 32) + st)) * TILE_US;

    // K: 512 tasks = 32 rows x 16 chunks(8 elems), fp16
    #pragma unroll
    for (int it = 0; it < 2; ++it) {
        int task = tid + it * 256;
        int r = task >> 4, c16 = task & 15;            // d = c16*8
        const float* kp = kg + (((size_t)(b * T_ + st * 32 + r)) * NKV_ + kvh) * D_ + c16 * 8;
        H8 hu;
        #pragma unroll
        for (int j = 0; j < 8; ++j) hu.h[j] = (_Float16)kp[j];
        int c = c16 >> 2, qd = c16 & 3, hi = r >> 4, ln = r & 15;
        int slot = (c * 2 + hi) * 64 + qd * 16 + ln;
        *(f16x8*)(base + slot * 8) = hu.v;
    }
    // V^T: 512 tasks = 128 d x 4 s-chunks(8 s), bf16
    #pragma unroll
    for (int it = 0; it < 2; ++it) {
        int task = tid + it * 256;
        int d = task & 127, sc = task >> 7;
        const float* vp = vg + (((size_t)(b * T_ + st * 32 + sc * 8)) * NKV_ + kvh) * D_ + d;
        U8 pk;
        #pragma unroll
        for (int j = 0; j < 8; ++j) pk.us[j] = f2bf(vp[j * (NKV_ * D_)]);
        int slot = (d >> 4) * 64 + sc * 16 + (d & 15);
        *(bf16x8*)(base + 4096 + slot * 8) = pk.v;
    }
}

// ---------------- prep 2: per-row segment start indices ----------------
__global__ __launch_bounds__(256)
void prep_sstart(const int* __restrict__ seg, int* __restrict__ sstart)
{
    int idx = blockIdx.x * 256 + threadIdx.x;
    int b = idx >> 11, t = idx & (T_ - 1);
    const int* sb = seg + b * T_;
    int target = sb[t];
    int lo = 0, hi = t;
    while (lo < hi) { int mid = (lo + hi) >> 1; if (sb[mid] < target) lo = mid + 1; else hi = mid; }
    sstart[idx] = lo;
}

// ---------------- main attention kernel (4 independent waves per block, no LDS, no barriers) ----------------
__global__ __launch_bounds__(256)
void attn_fwd(const float* __restrict__ qg,
              const int* __restrict__ sstart,
              const unsigned short* __restrict__ ws,
              float* __restrict__ outg)
{
    const int tid  = threadIdx.x;
    const int wave = tid >> 6;
    const int lane = tid & 63;
    const int qd   = lane >> 4;
    const int ln   = lane & 15;

    const int kvh  = blockIdx.x;             // kv head; 4 waves = its 4 q-heads
    const int head = kvh * 4 + wave;
    const int j    = blockIdx.y;             // folded chunk-pair index 0..63
    const int b    = blockIdx.z;

    const unsigned short* wsbase =
        ws + ((size_t)((b * NKV_ + kvh) * (T_ / 32))) * TILE_US + lane * 8;

    // load K(tile) and V(tile) fragments into named register buffers
#define LOADKV(KB, VB, tl) do {                                                \
        const unsigned short* _tb = wsbase + (size_t)(tl) * TILE_US;           \
        _Pragma("unroll")                                                      \
        for (int _c = 0; _c < 4; ++_c) {                                       \
            KB[_c][0] = *(const f16x8*)(_tb + (_c * 2 + 0) * 512);             \
            KB[_c][1] = *(const f16x8*)(_tb + (_c * 2 + 1) * 512);             \
        }                                                                      \
        _Pragma("unroll")                                                      \
        for (int _s = 0; _s < 8; ++_s)                                         \
            VB[_s] = *(const bf16x8*)(_tb + 4096 + _s * 512);                  \
    } while (0)

    // Swapped QK: S = mfma(Kfrag, Qfrag) -> lane(qd,ln) holds
    // S[kv = s0 + qd*4 + r (+16 for S1)][q-row = ln].  P transpose to the PV
    // A-operand layout (pa[k=qd*8+j] for q-row=ln) is 4 cvt_pk + 4 permlane swaps.
#define COMPUTE(KB, VB, TL) do {                                               \
        const int _s0 = (TL) * 32;                                             \
        f32x4 S0 = {0.f,0.f,0.f,0.f}, S1 = {0.f,0.f,0.f,0.f};                  \
        __builtin_amdgcn_s_setprio(1);                                         \
        _Pragma("unroll")                                                      \
        for (int c = 0; c < 4; ++c) {                                          \
            S0 = __builtin_amdgcn_mfma_f32_16x16x32_f16(KB[c][0], qh[c], S0,0,0,0); \
            S1 = __builtin_amdgcn_mfma_f32_16x16x32_f16(KB[c][1], qh[c], S1,0,0,0); \
            S0 = __builtin_amdgcn_mfma_f32_16x16x32_f16(KB[c][0], ql[c], S0,0,0,0); \
            S1 = __builtin_amdgcn_mfma_f32_16x16x32_f16(KB[c][1], ql[c], S1,0,0,0); \
        }                                                                      \
        __builtin_amdgcn_s_setprio(0);                                         \
        float p0[4], p1[4];                                                    \
        if (_s0 >= wave_rs_max && _s0 + 31 <= wave_row_min) {                  \
            _Pragma("unroll")                                                  \
            for (int r = 0; r < 4; ++r) {                                      \
                p0[r] = exp2f(S0[r]);                                          \
                p1[r] = exp2f(S1[r]);                                          \
            }                                                                  \
        } else {                                                               \
            _Pragma("unroll")                                                  \
            for (int r = 0; r < 4; ++r) {                                      \
                int kv0 = _s0 + qd * 4 + r;                                    \
                int kv1 = kv0 + 16;                                            \
                float sv0 = (kv0 >= rs_l && kv0 <= trow_l) ? S0[r] : MASKV;    \
                float sv1 = (kv1 >= rs_l && kv1 <= trow_l) ? S1[r] : MASKV;    \
                p0[r] = exp2f(sv0);                                            \
                p1[r] = exp2f(sv1);                                            \
            }                                                                  \
        }                                                                      \
        l_lane += (p0[0] + p0[1]) + (p0[2] + p0[3])                            \
                + (p1[0] + p1[1]) + (p1[2] + p1[3]);                           \
        PKW c0, c1, c2, c3;                                                    \
        c0.h = (bf16x2){(__bf16)p0[0], (__bf16)p0[1]};                         \
        c1.h = (bf16x2){(__bf16)p0[2], (__bf16)p0[3]};                         \
        c2.h = (bf16x2){(__bf16)p1[0], (__bf16)p1[1]};                         \
        c3.h = (bf16x2){(__bf16)p1[2], (__bf16)p1[3]};                         \
        unsigned int w0 = c0.u, w1 = c1.u, w2 = c2.u, w3 = c3.u;               \
        pl32swap(w0, w2); pl32swap(w1, w3);                                    \
        pl16swap(w0, w2); pl16swap(w1, w3);                                    \
        PA4 pw; pw.u[0] = w0; pw.u[1] = w1; pw.u[2] = w2; pw.u[3] = w3;        \
        bf16x8 pa = pw.v;                                                      \
        __builtin_amdgcn_s_setprio(1);                                         \
        _Pragma("unroll")                                                      \
        for (int sub = 0; sub < 8; ++sub)                                      \
            O[sub] = __builtin_amdgcn_mfma_f32_16x16x32_bf16(pa, VB[sub], O[sub],0,0,0); \
        __builtin_amdgcn_s_setprio(0);                                         \
    } while (0)

    // Folded pair: phase 0 = heavy 16-row chunk (127-j), phase 1 = light (j).
    for (int phase = 0; phase < 2; ++phase) {
        const int chunk = (phase == 0) ? (2 * (int)gridDim.y - 1 - j) : j;
        const int t0 = chunk * 16;

        // ---- preload Q fragments, scaled by log2(e), fp16 hi/lo split ----
        f16x8 qh[4], ql[4];
        {
            const float* qrow =
                qg + (((size_t)(b * T_ + (t0 + ln)) * NQ_) + head) * D_;
            #pragma unroll
            for (int c = 0; c < 4; ++c) {
                float4 a  = *(const float4*)(qrow + c * 32 + qd * 8);
                float4 b2 = *(const float4*)(qrow + c * 32 + qd * 8 + 4);
                float xs[8] = {a.x, a.y, a.z, a.w, b2.x, b2.y, b2.z, b2.w};
                H8 hu, lu;
                #pragma unroll
                for (int jj = 0; jj < 8; ++jj) {
                    float x = xs[jj] * LOG2E;
                    _Float16 h = (_Float16)x;
                    hu.h[jj] = h;
                    lu.h[jj] = (_Float16)(x - (float)h);
                }
                qh[c] = hu.v; ql[c] = lu.v;
            }
        }

        // ---- per-lane row info (this lane's q-row is ln within the wave) ----
        const int trow_l = t0 + ln;
        const int rs_l   = sstart[b * T_ + trow_l];
        const int wave_rs_max  = sstart[b * T_ + t0 + 15];   // sorted -> max of the 16 rows
        const int wave_row_min = t0;

        const int tile0   = sstart[b * T_ + t0] >> 5;        // wave-uniform
        const int n_tiles = ((t0 + 15) >> 5) + 1;

        f32x4 O[8];
        #pragma unroll
        for (int k = 0; k < 8; ++k) O[k] = (f32x4){0.f, 0.f, 0.f, 0.f};
        float l_lane = 0.f;      // softmax denom for q-row = ln (partial over this qd's kv slots)

        f16x8  kA[4][2], kB_[4][2];
        bf16x8 vA[8], vB_[8];

        int t = tile0;
        LOADKV(kA, vA, t);                      // prologue
        while (t + 1 < n_tiles) {
            LOADKV(kB_, vB_, t + 1);            // prefetch under compute(A)
            COMPUTE(kA, vA, t);
            if (t + 2 < n_tiles) LOADKV(kA, vA, t + 2);
            COMPUTE(kB_, vB_, t + 1);
            t += 2;
        }
        if (t < n_tiles) COMPUTE(kA, vA, t);

        // ---- epilogue: reduce l across qd groups, redistribute via shfl, store ----
        float l = l_lane;
        l += __shfl_xor(l, 16);
        l += __shfl_xor(l, 32);
        const float invl = 1.0f / l;           // per lane: denom for q-row = ln
        int trow[4];
        float inv[4];
        #pragma unroll
        for (int r = 0; r < 4; ++r) {
            trow[r] = t0 + qd * 4 + r;
            inv[r]  = __shfl(invl, qd * 4 + r);   // lane (qd*4+r) holds denom for that row
        }
        #pragma unroll
        for (int sub = 0; sub < 8; ++sub) {
            #pragma unroll
            for (int r = 0; r < 4; ++r) {
                outg[(((size_t)(b * T_ + trow[r]) * NQ_) + head) * D_ + sub * 16 + ln] =
                    O[sub][r] * inv[r];
            }
        }
    }

#undef LOADKV
#undef COMPUTE
}

// ---------------- fallback (no-ws path) ----------------
#define KSTR 136
#define VSTR 40
#define PSTR 40
static __device__ __forceinline__ float bf2f(unsigned short h) {
    union { unsigned int u; float f; } c; c.u = (unsigned int)h << 16; return c.f;
}
__global__ __launch_bounds__(256)
void attn_fwd_fb(const float* __restrict__ qg,
                 const float* __restrict__ kg,
                 const float* __restrict__ vg,
                 const int* __restrict__ seg,
                 float* __restrict__ outg)
{
    __shared__ unsigned short sKh[32 * KSTR];
    __shared__ unsigned short sKl[32 * KSTR];
    __shared__ unsigned short sVt[128 * VSTR];
    __shared__ unsigned short sP[4][16 * PSTR];

    const int tid  = threadIdx.x;
    const int wave = tid >> 6;
    const int lane = tid & 63;
    const int qd   = lane >> 4;
    const int ln   = lane & 15;
    const int t0   = ((int)gridDim.x - 1 - (int)blockIdx.x) * 64;
    const int head = blockIdx.y;
    const int kvh  = head >> 2;
    const int b    = blockIdx.z;

    bf16x8 qh[4], ql[4];
    {
        const float* qrow =
            qg + (((size_t)(b * T_ + (t0 + wave * 16 + ln)) * NQ_) + head) * D_;
        #pragma unroll
        for (int c = 0; c < 4; ++c) {
            float4 a  = *(const float4*)(qrow + c * 32 + qd * 8);
            float4 b2 = *(const float4*)(qrow + c * 32 + qd * 8 + 4);
            float xs[8] = {a.x, a.y, a.z, a.w, b2.x, b2.y, b2.z, b2.w};
            U8 hu, lu;
            #pragma unroll
            for (int j = 0; j < 8; ++j) {
                unsigned short h = f2bf(xs[j]);
                hu.us[j] = h;
                lu.us[j] = f2bf(xs[j] - bf2f(h));
            }
            qh[c] = hu.v; ql[c] = lu.v;
        }
    }
    const int* sb = seg + (size_t)b * T_;
    int qseg[4];
    #pragma unroll
    for (int r = 0; r < 4; ++r) qseg[r] = sb[t0 + wave * 16 + qd * 4 + r];
    int tile0;
    {
        int target = sb[t0];
        int lo = 0, hi = t0;
        while (lo < hi) { int mid = (lo + hi) >> 1; if (sb[mid] < target) lo = mid + 1; else hi = mid; }
        tile0 = lo >> 5;
    }
    f32x4 O[8];
    #pragma unroll
    for (int i = 0; i < 8; ++i) O[i] = (f32x4){0.f, 0.f, 0.f, 0.f};
    float m_prev[4], l_lane[4];
    #pragma unroll
    for (int r = 0; r < 4; ++r) { m_prev[r] = MASKV; l_lane[r] = 0.f; }
    const int n_tiles = t0 / 32 + 2;

    for (int tile = tile0; tile < n_tiles; ++tile) {
        const int s0 = tile * 32;
        __syncthreads();
        #pragma unroll
        for (int it = 0; it < 2; ++it) {
            int task = tid + it * 256;
            int r = task >> 4, d = (task & 15) * 8;
            const float* kp = kg + (((size_t)(b * T_ + s0 + r) * NKV_) + kvh) * D_ + d;
            float4 a  = *(const float4*)(kp);
            float4 b2 = *(const float4*)(kp + 4);
            float xs[8] = {a.x, a.y, a.z, a.w, b2.x, b2.y, b2.z, b2.w};
            U8 hu, lu;
            #pragma unroll
            for (int j = 0; j < 8; ++j) {
                unsigned short h = f2bf(xs[j]);
                hu.us[j] = h;
                lu.us[j] = f2bf(xs[j] - bf2f(h));
            }
            *(bf16x8*)(sKh + r * KSTR + d) = hu.v;
            *(bf16x8*)(sKl + r * KSTR + d) = lu.v;
        }
        #pragma unroll
        for (int it = 0; it < 2; ++it) {
            int task = tid + it * 256;
            int d = task & 127, sg = task >> 7;
            const float* vp = vg + (((size_t)(b * T_ + s0 + sg * 8) * NKV_) + kvh) * D_ + d;
            U8 pk;
            #pragma unroll
            for (int j = 0; j < 8; ++j) pk.us[j] = f2bf(vp[j * (NKV_ * D_)]);
            *(bf16x8*)(sVt + d * VSTR + sg * 8) = pk.v;
        }
        __syncthreads();

        f32x4 S0 = {0.f,0.f,0.f,0.f}, S1 = {0.f,0.f,0.f,0.f};
        #pragma unroll
        for (int c = 0; c < 4; ++c) {
            bf16x8 kh0 = *(const bf16x8*)(sKh + ln * KSTR + c * 32 + qd * 8);
            bf16x8 kh1 = *(const bf16x8*)(sKh + (16 + ln) * KSTR + c * 32 + qd * 8);
            bf16x8 kl0 = *(const bf16x8*)(sKl + ln * KSTR + c * 32 + qd * 8);
            bf16x8 kl1 = *(const bf16x8*)(sKl + (16 + ln) * KSTR + c * 32 + qd * 8);
            S0 = __builtin_amdgcn_mfma_f32_16x16x32_bf16(qh[c], kh0, S0, 0, 0, 0);
            S1 = __builtin_amdgcn_mfma_f32_16x16x32_bf16(qh[c], kh1, S1, 0, 0, 0);
            S0 = __builtin_amdgcn_mfma_f32_16x16x32_bf16(qh[c], kl0, S0, 0, 0, 0);
            S1 = __builtin_amdgcn_mfma_f32_16x16x32_bf16(qh[c], kl1, S1, 0, 0, 0);
            S0 = __builtin_amdgcn_mfma_f32_16x16x32_bf16(ql[c], kh0, S0, 0, 0, 0);
            S1 = __builtin_amdgcn_mfma_f32_16x16x32_bf16(ql[c], kh1, S1, 0, 0, 0);
        }
        const int ks0 = sb[s0 + ln];
        const int ks1 = sb[s0 + 16 + ln];
        float p0[4], p1[4], alpha[4];
        #pragma unroll
        for (int r = 0; r < 4; ++r) {
            const int trow = t0 + wave * 16 + qd * 4 + r;
            float s0v = ((s0 + ln <= trow) && (ks0 == qseg[r])) ? S0[r] : MASKV;
            float s1v = ((s0 + 16 + ln <= trow) && (ks1 == qseg[r])) ? S1[r] : MASKV;
            float mx = fmaxf(s0v, s1v);
            mx = fmaxf(mx, __shfl_xor(mx, 1));
            mx = fmaxf(mx, __shfl_xor(mx, 2));
            mx = fmaxf(mx, __shfl_xor(mx, 4));
            mx = fmaxf(mx, __shfl_xor(mx, 8));
            const float mn = fmaxf(m_prev[r], mx);
            alpha[r] = __expf(m_prev[r] - mn);
            p0[r] = __expf(s0v - mn);
            p1[r] = __expf(s1v - mn);
            l_lane[r] = alpha[r] * l_lane[r] + p0[r] + p1[r];
            m_prev[r] = mn;
        }
        #pragma unroll
        for (int i = 0; i < 8; ++i) {
            O[i][0] *= alpha[0]; O[i][1] *= alpha[1];
            O[i][2] *= alpha[2]; O[i][3] *= alpha[3];
        }
        {
            unsigned short* pw = sP[wave] + (qd * 4) * PSTR + ln;
            #pragma unroll
            for (int r = 0; r < 4; ++r) {
                pw[r * PSTR]      = f2bf(p0[r]);
                pw[r * PSTR + 16] = f2bf(p1[r]);
            }
        }
        asm volatile("s_waitcnt lgkmcnt(0)" ::: "memory");
        bf16x8 pa = *(const bf16x8*)(sP[wave] + ln * PSTR + qd * 8);
        #pragma unroll
        for (int sub = 0; sub < 8; ++sub) {
            bf16x8 bv = *(const bf16x8*)(sVt + (sub * 16 + ln) * VSTR + qd * 8);
            O[sub] = __builtin_amdgcn_mfma_f32_16x16x32_bf16(pa, bv, O[sub], 0, 0, 0);
        }
    }
    float inv[4];
    #pragma unroll
    for (int r = 0; r < 4; ++r) {
        float l = l_lane[r];
        l += __shfl_xor(l, 1);
        l += __shfl_xor(l, 2);
        l += __shfl_xor(l, 4);
        l += __shfl_xor(l, 8);
        inv[r] = 1.0f / l;
    }
    #pragma unroll
    for (int sub = 0; sub < 8; ++sub) {
        #pragma unroll
        for (int r = 0; r < 4; ++r) {
            const int trow = t0 + wave * 16 + qd * 4 + r;
            outg[(((size_t)(b * T_ + trow) * NQ_) + head) * D_ + sub * 16 + ln] =
                O[sub][r] * inv[r];
        }
    }
}

extern "C" void kernel_launch(void* const* d_in, const int* in_sizes, int n_in,
                              void* d_out, int out_size, void* d_ws, size_t ws_size,
                              hipStream_t stream) {
    const float* q  = (const float*)d_in[0];
    const float* k  = (const float*)d_in[1];
    const float* v  = (const float*)d_in[2];
    const int*   sg = (const int*)d_in[3];
    float*       o  = (float*)d_out;
    if (ws_size >= WS_NEED) {
        unsigned short* ws = (unsigned short*)d_ws;
        int* sstart = (int*)((char*)d_ws + WS_TILES_BYTES);
        prep<<<dim3(T_ / 32, NKV_, B_), dim3(256), 0, stream>>>(k, v, ws);
        prep_sstart<<<dim3(B_ * T_ / 256), dim3(256), 0, stream>>>(sg, sstart);
        attn_fwd<<<dim3(NKV_, T_ / 32, B_), dim3(256), 0, stream>>>(q, sstart, ws, o);
    } else {
        attn_fwd_fb<<<dim3(T_ / 64, NQ_, B_), dim3(256), 0, stream>>>(q, k, v, sg, o);
    }
}